// Round 1
// 130.623 us; speedup vs baseline: 1.0129x; 1.0129x over previous
//
#include <hip/hip_runtime.h>

#define NUM_FIELDS 10
#define ROW 128              // 2 * EMB floats per embedding row
#define WAVES_PER_BLOCK 4    // 256 threads
#define SAMPLES_PER_BLOCK 8  // 2 samples per wave * 4 waves

// Each wave handles 2 samples: lanes 0-31 -> sample b0, lanes 32-63 -> sample b1.
// Within a 32-lane half, lane hl owns dims [4*hl, 4*hl+4) via one float4 load per
// field: hl<16 covers dims 0-63 (FM order-2), hl>=16 covers dims 64-127 (ANOVA
// order-3). All lanes accumulate power sums p1/p2/p3 branch-free; the per-dim
// closed forms (Newton identities) are selected only in the epilogue:
//   e2 = (p1^2 - p2)/2,  e3 = (p1^3 - 3 p1 p2 + 2 p3)/6
__global__ __launch_bounds__(256) void fm_ho_kernel(
    const int* __restrict__ x, const int* __restrict__ offsets,
    const float* __restrict__ W_emb, const float* __restrict__ W_lin,
    const float* __restrict__ bias, float* __restrict__ out, int batch)
{
    const int lane = threadIdx.x & 63;
    const int wave = threadIdx.x >> 6;
    const int half = lane >> 5;   // which of the wave's 2 samples
    const int hl   = lane & 31;   // lane within the 32-lane half
    const int b = (blockIdx.x * WAVES_PER_BLOCK + wave) * 2 + half;
    if (b >= batch) return;

    // Linear term: lanes hl<10 fetch their field's W_lin entry directly from
    // memory (avoids runtime-indexing the ids[] register array -> scratch).
    float lin = 0.f;
    if (hl < NUM_FIELDS)
        lin = W_lin[x[b * NUM_FIELDS + hl] + offsets[hl]];

    // 10 indices for this lane's sample, vectorized as 5x int2 (8B-aligned:
    // b*10*4 bytes is a multiple of 8). Uniform address within each half.
    int ids[NUM_FIELDS];
    {
        const int2* xp = reinterpret_cast<const int2*>(x + b * NUM_FIELDS);
        int2 p0 = xp[0], p1 = xp[1], p2 = xp[2], p3 = xp[3], p4 = xp[4];
        ids[0] = p0.x; ids[1] = p0.y; ids[2] = p1.x; ids[3] = p1.y;
        ids[4] = p2.x; ids[5] = p2.y; ids[6] = p3.x; ids[7] = p3.y;
        ids[8] = p4.x; ids[9] = p4.y;
#pragma unroll
        for (int f = 0; f < NUM_FIELDS; ++f) ids[f] += offsets[f];
    }

    // Power sums over fields, 4 dims per lane. One float4 (16B) load per field
    // per lane: 64 lanes x 16B = 1 KiB per instruction (coalescing sweet spot).
    float4 s1 = make_float4(0.f, 0.f, 0.f, 0.f);
    float4 s2 = s1, s3 = s1;
#pragma unroll
    for (int f = 0; f < NUM_FIELDS; ++f) {
        const float4 v = *reinterpret_cast<const float4*>(
            W_emb + (size_t)ids[f] * ROW + 4 * hl);
        const float tx = v.x * v.x, ty = v.y * v.y,
                    tz = v.z * v.z, tw = v.w * v.w;
        s1.x += v.x; s1.y += v.y; s1.z += v.z; s1.w += v.w;
        s2.x += tx;  s2.y += ty;  s2.z += tz;  s2.w += tw;
        s3.x = fmaf(tx, v.x, s3.x); s3.y = fmaf(ty, v.y, s3.y);
        s3.z = fmaf(tz, v.z, s3.z); s3.w = fmaf(tw, v.w, s3.w);
    }

    // Per-dim closed forms; branch is epilogue-only and half-uniform.
    float v;
    if (hl < 16) {
        // FM pairs: sum_d 0.5*(p1^2 - p2)
        v = 0.5f * ((s1.x * s1.x - s2.x) + (s1.y * s1.y - s2.y)
                  + (s1.z * s1.z - s2.z) + (s1.w * s1.w - s2.w));
    } else {
        // ANOVA triples: sum_d (p1^3 - 3 p1 p2 + 2 p3)/6
        v = ((s1.x * (s1.x * s1.x - 3.f * s2.x) + 2.f * s3.x)
           + (s1.y * (s1.y * s1.y - 3.f * s2.y) + 2.f * s3.y)
           + (s1.z * (s1.z * s1.z - 3.f * s2.z) + 2.f * s3.z)
           + (s1.w * (s1.w * s1.w - 3.f * s2.w) + 2.f * s3.w)) * (1.f / 6.f);
    }
    v += lin;

    // Butterfly reduction within each 32-lane half (xor offsets < 32 never
    // cross the half boundary).
#pragma unroll
    for (int off = 16; off; off >>= 1)
        v += __shfl_xor(v, off, 64);

    if (hl == 0) {
        const float y = v + bias[0];
        out[b] = y > 0.f ? y : 0.f;
    }
}

extern "C" void kernel_launch(void* const* d_in, const int* in_sizes, int n_in,
                              void* d_out, int out_size, void* d_ws, size_t ws_size,
                              hipStream_t stream) {
    const int*   x       = (const int*)d_in[0];
    const int*   offsets = (const int*)d_in[1];
    const float* W_emb   = (const float*)d_in[2];
    const float* W_lin   = (const float*)d_in[3];
    const float* bias    = (const float*)d_in[4];
    float*       out     = (float*)d_out;

    const int batch = in_sizes[0] / NUM_FIELDS; // 16384
    const int grid  = (batch + SAMPLES_PER_BLOCK - 1) / SAMPLES_PER_BLOCK;
    hipLaunchKernelGGL(fm_ho_kernel, dim3(grid), dim3(256), 0, stream,
                       x, offsets, W_emb, W_lin, bias, out, batch);
}

// Round 2
// 130.118 us; speedup vs baseline: 1.0169x; 1.0039x over previous
//
#include <hip/hip_runtime.h>

#define NUM_FIELDS 10
#define ROW 128              // 2 * EMB floats per embedding row
#define WAVES_PER_BLOCK 4    // 256 threads
#define SAMPLES_PER_BLOCK 8  // 2 samples per wave * 4 waves

// Each wave handles 2 samples: lanes 0-31 -> sample b0, lanes 32-63 -> sample b1.
// Within a 32-lane half, lane hl owns dims [4*hl, 4*hl+4) via one float4 load per
// field: hl<16 covers dims 0-63 (FM order-2), hl>=16 covers dims 64-127 (ANOVA
// order-3). Newton identities in the epilogue:
//   e2 = (p1^2 - p2)/2,  e3 = (p1^3 - 3 p1 p2 + 2 p3)/6
//
// Latency-oriented layout: both samples' indices are loaded through a
// wave-UNIFORM pointer (s_load via constant cache, off the VMEM path), the
// linear term is summed entirely on the scalar unit (uniform W_lin loads),
// and the vector pipe issues only the 10 W_emb gathers + 1 store.
__global__ __launch_bounds__(256) void fm_ho_kernel(
    const int* __restrict__ x, const int* __restrict__ offsets,
    const float* __restrict__ W_emb, const float* __restrict__ W_lin,
    const float* __restrict__ bias, float* __restrict__ out, int batch)
{
    const int lane  = threadIdx.x & 63;
    // Force wave-uniformity so index math stays in SGPRs.
    const int waveu = __builtin_amdgcn_readfirstlane(threadIdx.x >> 6);
    const int half  = lane >> 5;   // which of the wave's 2 samples
    const int hl    = lane & 31;   // lane within the 32-lane half
    const int pair  = blockIdx.x * WAVES_PER_BLOCK + waveu; // uniform
    const int b0    = pair * 2;                             // uniform
    const int b     = b0 + half;
    if (b0 + 1 >= batch && b >= batch) return; // grid is exact for 16384

    // Both samples' 10 indices via a uniform pointer -> scalar loads.
    const int* xw = x + b0 * NUM_FIELDS; // uniform address
    int idA[NUM_FIELDS], idB[NUM_FIELDS];
#pragma unroll
    for (int f = 0; f < NUM_FIELDS; ++f) {
        const int off = offsets[f];            // uniform (s_load)
        idA[f] = xw[f] + off;                  // uniform (s_load + s_add)
        idB[f] = xw[NUM_FIELDS + f] + off;
    }

    // Linear term on the scalar path: uniform W_lin loads, summed in SGPR/VGPR
    // without touching the vector memory pipe.
    float linA = 0.f, linB = 0.f;
#pragma unroll
    for (int f = 0; f < NUM_FIELDS; ++f) {
        linA += W_lin[idA[f]];
        linB += W_lin[idB[f]];
    }

    // Power sums over fields, 4 dims per lane. One float4 (16B) load per field
    // per lane: 64 lanes x 16B = 1 KiB per instruction. Per-lane row id is a
    // single v_cndmask from the SGPR-resident idA/idB.
    float4 s1 = make_float4(0.f, 0.f, 0.f, 0.f);
    float4 s2 = s1, s3 = s1;
#pragma unroll
    for (int f = 0; f < NUM_FIELDS; ++f) {
        const int id = half ? idB[f] : idA[f];
        const float4 v = *reinterpret_cast<const float4*>(
            W_emb + (size_t)id * ROW + 4 * hl);
        const float tx = v.x * v.x, ty = v.y * v.y,
                    tz = v.z * v.z, tw = v.w * v.w;
        s1.x += v.x; s1.y += v.y; s1.z += v.z; s1.w += v.w;
        s2.x += tx;  s2.y += ty;  s2.z += tz;  s2.w += tw;
        s3.x = fmaf(tx, v.x, s3.x); s3.y = fmaf(ty, v.y, s3.y);
        s3.z = fmaf(tz, v.z, s3.z); s3.w = fmaf(tw, v.w, s3.w);
    }

    // Per-dim closed forms; branch is epilogue-only and half-uniform.
    float v;
    if (hl < 16) {
        // FM pairs: sum_d 0.5*(p1^2 - p2)
        v = 0.5f * ((s1.x * s1.x - s2.x) + (s1.y * s1.y - s2.y)
                  + (s1.z * s1.z - s2.z) + (s1.w * s1.w - s2.w));
    } else {
        // ANOVA triples: sum_d (p1^3 - 3 p1 p2 + 2 p3)/6
        v = ((s1.x * (s1.x * s1.x - 3.f * s2.x) + 2.f * s3.x)
           + (s1.y * (s1.y * s1.y - 3.f * s2.y) + 2.f * s3.y)
           + (s1.z * (s1.z * s1.z - 3.f * s2.z) + 2.f * s3.z)
           + (s1.w * (s1.w * s1.w - 3.f * s2.w) + 2.f * s3.w)) * (1.f / 6.f);
    }

    // Butterfly reduction within each 32-lane half (xor offsets < 32 never
    // cross the half boundary).
#pragma unroll
    for (int off = 16; off; off >>= 1)
        v += __shfl_xor(v, off, 64);

    if (hl == 0) {
        const float y = v + (half ? linB : linA) + bias[0];
        out[b] = y > 0.f ? y : 0.f;
    }
}

extern "C" void kernel_launch(void* const* d_in, const int* in_sizes, int n_in,
                              void* d_out, int out_size, void* d_ws, size_t ws_size,
                              hipStream_t stream) {
    const int*   x       = (const int*)d_in[0];
    const int*   offsets = (const int*)d_in[1];
    const float* W_emb   = (const float*)d_in[2];
    const float* W_lin   = (const float*)d_in[3];
    const float* bias    = (const float*)d_in[4];
    float*       out     = (float*)d_out;

    const int batch = in_sizes[0] / NUM_FIELDS; // 16384
    const int grid  = (batch + SAMPLES_PER_BLOCK - 1) / SAMPLES_PER_BLOCK;
    hipLaunchKernelGGL(fm_ho_kernel, dim3(grid), dim3(256), 0, stream,
                       x, offsets, W_emb, W_lin, bias, out, batch);
}